// Round 1
// baseline (887.618 us; speedup 1.0000x reference)
//
#include <hip/hip_runtime.h>
#include <hip/hip_bf16.h>
#include <stdint.h>

// Problem constants (CausalSelfAttention_22703197127379)
#define T_DIM 8192
#define E_DIM 4096
#define NQH   32
#define HD    128
#define QSZ   (NQH * HD)          // 4096
#define QKV_COLS 6144             // Q_SIZE + 2*KV_SIZE (w_qkv leading dim)

typedef unsigned short u16;
typedef __attribute__((ext_vector_type(8))) short   bf16x8;
typedef __attribute__((ext_vector_type(4))) float   f32x4;
typedef __attribute__((ext_vector_type(4))) unsigned short u16x4;

__device__ __forceinline__ u16 f2bf(float f) {
    uint32_t u = __float_as_uint(f);
    u += 0x7fffu + ((u >> 16) & 1u);   // round-to-nearest-even
    return (u16)(u >> 16);
}
__device__ __forceinline__ float bf2f(u16 u) {
    return __uint_as_float(((uint32_t)u) << 16);
}

// async global->LDS, 16 bytes per lane (dest must be wave-uniform base + lane*16)
__device__ __forceinline__ void gload_lds16(u16* lds, const u16* g) {
    __builtin_amdgcn_global_load_lds(
        (const __attribute__((address_space(1))) uint32_t*)g,
        (__attribute__((address_space(3))) uint32_t*)lds,
        16, 0, 0);
}

// ---------------- fp32 -> bf16 elementwise convert (vectorized) ----------------
__global__ void convert_f32_bf16(const float* __restrict__ in, u16* __restrict__ out, size_t n4) {
    size_t i = (size_t)blockIdx.x * blockDim.x + threadIdx.x;
    size_t stride = (size_t)gridDim.x * blockDim.x;
    for (; i < n4; i += stride) {
        float4 v = ((const float4*)in)[i];
        u16x4 o;
        o.x = f2bf(v.x); o.y = f2bf(v.y); o.z = f2bf(v.z); o.w = f2bf(v.w);
        ((u16x4*)out)[i] = o;
    }
}

// ---------------- fp32 [K][ldW] (col slice) -> bf16 transposed [N][K] ----------------
__global__ void transpose_conv(const float* __restrict__ W, u16* __restrict__ Wt,
                               int K, int N, int ldW, int colOff) {
    __shared__ float tile[32][33];
    const int tx = threadIdx.x, ty = threadIdx.y;
    const int n0 = blockIdx.x * 32, k0 = blockIdx.y * 32;
#pragma unroll
    for (int j = 0; j < 4; ++j) {
        int k = k0 + ty + j * 8;
        tile[ty + j * 8][tx] = W[(size_t)k * ldW + colOff + n0 + tx];
    }
    __syncthreads();
#pragma unroll
    for (int j = 0; j < 4; ++j) {
        int n = n0 + ty + j * 8;
        Wt[(size_t)n * K + k0 + tx] = f2bf(tile[tx][ty + j * 8]);
    }
}

// ---------------- NeoX RoPE, in-place on bf16 Q [T][QSZ] ----------------
__global__ void rope_kernel(u16* __restrict__ Q, const int* __restrict__ pos) {
    const size_t total = (size_t)T_DIM * (QSZ / 2);   // one thread per (d, d+64) pair
    size_t stride = (size_t)gridDim.x * blockDim.x;
    for (size_t idx = (size_t)blockIdx.x * blockDim.x + threadIdx.x; idx < total; idx += stride) {
        int t = (int)(idx >> 11);          // / 2048
        int r = (int)(idx & 2047);
        int h = r >> 6;
        int d = r & 63;
        size_t base = (size_t)t * QSZ + h * HD;
        float x1 = bf2f(Q[base + d]);
        float x2 = bf2f(Q[base + d + 64]);
        float inv = powf(10000.0f, -(float)d * (1.0f / 64.0f));
        float fr  = (float)pos[t] * inv;
        float s, c;
        sincosf(fr, &s, &c);
        Q[base + d]      = f2bf(x1 * c - x2 * s);
        Q[base + d + 64] = f2bf(x2 * c + x1 * s);
    }
}

// ---------------- bf16 GEMM: C[M][N] = A[M][K] * Bt[N][K]^T ----------------
__device__ __forceinline__ void store_out(u16* p, float v)  { *p = f2bf(v); }
__device__ __forceinline__ void store_out(float* p, float v){ *p = v; }

template <typename OutT>
__global__ __launch_bounds__(256) void gemm_bt(const u16* __restrict__ A,
                                               const u16* __restrict__ Bt,
                                               OutT* __restrict__ C,
                                               int M, int N, int K) {
    __shared__ u16 Al[128 * 32];
    __shared__ u16 Bl[128 * 32];
    const int tid  = threadIdx.x;
    const int wave = tid >> 6;
    const int lane = tid & 63;
    const int wr = wave >> 1;          // wave row (0..1) -> 64 rows each
    const int wc = wave & 1;           // wave col (0..1) -> 64 cols each
    const int lr = lane & 15;
    const int lk = (lane >> 4) << 3;   // k offset 0,8,16,24
    const size_t rowBase = (size_t)blockIdx.y * 128;
    const size_t colBase = (size_t)blockIdx.x * 128;

    f32x4 acc[4][4];
#pragma unroll
    for (int i = 0; i < 4; ++i)
#pragma unroll
        for (int j = 0; j < 4; ++j)
            acc[i][j] = (f32x4){0.f, 0.f, 0.f, 0.f};

    // staging: 128x32 bf16 tile = 8KB = 512 x 16B chunks; 256 threads x 2 chunks
    const int c0 = tid, c1 = tid + 256;
    const u16* gA0 = A  + (rowBase + (c0 >> 2)) * (size_t)K + ((c0 & 3) << 3);
    const u16* gA1 = A  + (rowBase + (c1 >> 2)) * (size_t)K + ((c1 & 3) << 3);
    const u16* gB0 = Bt + (colBase + (c0 >> 2)) * (size_t)K + ((c0 & 3) << 3);
    const u16* gB1 = Bt + (colBase + (c1 >> 2)) * (size_t)K + ((c1 & 3) << 3);
    u16* lA0 = &Al[c0 * 8]; u16* lA1 = &Al[c1 * 8];
    u16* lB0 = &Bl[c0 * 8]; u16* lB1 = &Bl[c1 * 8];

    for (int kb = 0; kb < K; kb += 32) {
        gload_lds16(lA0, gA0 + kb);
        gload_lds16(lA1, gA1 + kb);
        gload_lds16(lB0, gB0 + kb);
        gload_lds16(lB1, gB1 + kb);
        __syncthreads();   // drains vmcnt: LDS tile ready

        bf16x8 a[4], b[4];
#pragma unroll
        for (int mi = 0; mi < 4; ++mi)
            a[mi] = *(const bf16x8*)&Al[(wr * 64 + mi * 16 + lr) * 32 + lk];
#pragma unroll
        for (int ni = 0; ni < 4; ++ni)
            b[ni] = *(const bf16x8*)&Bl[(wc * 64 + ni * 16 + lr) * 32 + lk];
#pragma unroll
        for (int mi = 0; mi < 4; ++mi)
#pragma unroll
            for (int ni = 0; ni < 4; ++ni)
                acc[mi][ni] = __builtin_amdgcn_mfma_f32_16x16x32_bf16(a[mi], b[ni], acc[mi][ni], 0, 0, 0);
        __syncthreads();   // compute done before next stage overwrites LDS
    }

    // epilogue: C/D layout col = lane&15, row = 4*(lane>>4) + r  [verified m89/m91]
#pragma unroll
    for (int mi = 0; mi < 4; ++mi)
#pragma unroll
        for (int ni = 0; ni < 4; ++ni)
#pragma unroll
            for (int r = 0; r < 4; ++r) {
                size_t row = rowBase + wr * 64 + mi * 16 + ((lane >> 4) << 2) + r;
                size_t col = colBase + wc * 64 + ni * 16 + lr;
                store_out(&C[row * (size_t)N + col], acc[mi][ni][r]);
            }
}

extern "C" void kernel_launch(void* const* d_in, const int* in_sizes, int n_in,
                              void* d_out, int out_size, void* d_ws, size_t ws_size,
                              hipStream_t stream) {
    const float* hidden    = (const float*)d_in[0];   // [T][E] fp32
    const int*   positions = (const int*)d_in[1];     // [T] int32
    const float* w_qkv     = (const float*)d_in[2];   // [E][6144] fp32
    const float* w_o       = (const float*)d_in[3];   // [QSZ][E] fp32
    float* out = (float*)d_out;                       // [T][E] fp32

    // workspace layout (bf16): H 64MB | WqT 32MB | WoT 32MB | Q 64MB = 192MB
    u16* Hb  = (u16*)d_ws;
    u16* WqT = Hb  + (size_t)T_DIM * E_DIM;
    u16* WoT = WqT + (size_t)QSZ * E_DIM;
    u16* Qb  = WoT + (size_t)E_DIM * QSZ;

    // 1) hidden fp32 -> bf16
    convert_f32_bf16<<<2048, 256, 0, stream>>>(hidden, Hb, (size_t)T_DIM * E_DIM / 4);

    // 2) weight transposes+converts: WqT[n][k] = w_qkv[k][n] (cols 0..4095), WoT[e][k] = w_o[k][e]
    dim3 tb(32, 8);
    transpose_conv<<<dim3(QSZ / 32, E_DIM / 32), tb, 0, stream>>>(w_qkv, WqT, E_DIM, QSZ, QKV_COLS, 0);
    transpose_conv<<<dim3(E_DIM / 32, QSZ / 32), tb, 0, stream>>>(w_o,   WoT, QSZ,   E_DIM, E_DIM,  0);

    // 3) Q = H @ Wq  (bf16 out)
    gemm_bt<u16><<<dim3(QSZ / 128, T_DIM / 128), 256, 0, stream>>>(Hb, WqT, Qb, T_DIM, QSZ, E_DIM);

    // 4) NeoX RoPE in place on Q
    rope_kernel<<<4096, 256, 0, stream>>>(Qb, positions);

    // 5) out = Q @ Wo  (fp32 out)
    gemm_bt<float><<<dim3(E_DIM / 128, T_DIM / 128), 256, 0, stream>>>(Qb, WoT, out, T_DIM, E_DIM, QSZ);
}

// Round 2
// 692.925 us; speedup vs baseline: 1.2810x; 1.2810x over previous
//
#include <hip/hip_runtime.h>
#include <hip/hip_bf16.h>
#include <stdint.h>

// Problem constants (CausalSelfAttention_22703197127379)
#define T_DIM 8192
#define E_DIM 4096
#define NQH   32
#define HD    128
#define QSZ   (NQH * HD)          // 4096
#define QKV_COLS 6144             // Q_SIZE + 2*KV_SIZE (w_qkv leading dim)

typedef unsigned short u16;
typedef __attribute__((ext_vector_type(8))) short   bf16x8;
typedef __attribute__((ext_vector_type(4))) float   f32x4;
typedef __attribute__((ext_vector_type(4))) unsigned short u16x4;

__device__ __forceinline__ u16 f2bf(float f) {
    uint32_t u = __float_as_uint(f);
    u += 0x7fffu + ((u >> 16) & 1u);   // round-to-nearest-even
    return (u16)(u >> 16);
}
__device__ __forceinline__ float bf2f(u16 u) {
    return __uint_as_float(((uint32_t)u) << 16);
}

// async global->LDS, 16 bytes per lane (dest = wave-uniform base + lane*16)
__device__ __forceinline__ void gload_lds16(u16* lds, const u16* g) {
    __builtin_amdgcn_global_load_lds(
        (const __attribute__((address_space(1))) uint32_t*)g,
        (__attribute__((address_space(3))) uint32_t*)lds,
        16, 0, 0);
}

// ---------------- fp32 -> bf16 elementwise convert (vectorized) ----------------
__global__ void convert_f32_bf16(const float* __restrict__ in, u16* __restrict__ out, size_t n4) {
    size_t i = (size_t)blockIdx.x * blockDim.x + threadIdx.x;
    size_t stride = (size_t)gridDim.x * blockDim.x;
    for (; i < n4; i += stride) {
        float4 v = ((const float4*)in)[i];
        u16x4 o;
        o.x = f2bf(v.x); o.y = f2bf(v.y); o.z = f2bf(v.z); o.w = f2bf(v.w);
        ((u16x4*)out)[i] = o;
    }
}

// ---------------- fp32 [K][ldW] (col slice) -> bf16 transposed [N][K] ----------------
__global__ void transpose_conv(const float* __restrict__ W, u16* __restrict__ Wt,
                               int K, int N, int ldW, int colOff) {
    __shared__ float tile[32][33];
    const int tx = threadIdx.x, ty = threadIdx.y;
    const int n0 = blockIdx.x * 32, k0 = blockIdx.y * 32;
#pragma unroll
    for (int j = 0; j < 4; ++j) {
        int k = k0 + ty + j * 8;
        tile[ty + j * 8][tx] = W[(size_t)k * ldW + colOff + n0 + tx];
    }
    __syncthreads();
#pragma unroll
    for (int j = 0; j < 4; ++j) {
        int n = n0 + ty + j * 8;
        Wt[(size_t)n * K + k0 + tx] = f2bf(tile[tx][ty + j * 8]);
    }
}

// ---------------- NeoX RoPE, in-place on bf16 Q [T][QSZ] ----------------
__global__ void rope_kernel(u16* __restrict__ Q, const int* __restrict__ pos) {
    const size_t total = (size_t)T_DIM * (QSZ / 2);   // one thread per (d, d+64) pair
    size_t stride = (size_t)gridDim.x * blockDim.x;
    for (size_t idx = (size_t)blockIdx.x * blockDim.x + threadIdx.x; idx < total; idx += stride) {
        int t = (int)(idx >> 11);          // / 2048
        int r = (int)(idx & 2047);
        int h = r >> 6;
        int d = r & 63;
        size_t base = (size_t)t * QSZ + h * HD;
        float x1 = bf2f(Q[base + d]);
        float x2 = bf2f(Q[base + d + 64]);
        float inv = powf(10000.0f, -(float)d * (1.0f / 64.0f));
        float fr  = (float)pos[t] * inv;
        float s, c;
        sincosf(fr, &s, &c);
        Q[base + d]      = f2bf(x1 * c - x2 * s);
        Q[base + d + 64] = f2bf(x2 * c + x1 * s);
    }
}

// ---------------- pipelined bf16 GEMM: C[M][N] = A[M][K] * Bt[N][K]^T ----------------
// 256x256 tile, BK=32, 4-stage LDS ring (128 KiB), 8 waves (2M x 4N),
// counted vmcnt(8) (2 K-tiles in flight), one barrier per K-step, setprio
// around the MFMA cluster. Ring safety: stage t+3 -> slot (t+3)&3 overwrites
// data last read at step t; barrier skew < 2 steps => no wave can still be
// reading it. vmcnt(8) before barrier B_t guarantees stage t+1 landed
// (own 8 newest outstanding = stages t+2,t+3) across all waves after B_t.
__device__ __forceinline__ void store_out(u16* p, float v)  { *p = f2bf(v); }
__device__ __forceinline__ void store_out(float* p, float v){ *p = v; }

#define SLOT_ELEMS 16384   // A 8192 + B 8192 u16 per stage (32 KB)

#define KSTEP(T, DO_STAGE, DO_WAIT, VM, DO_BAR)                                  \
  do {                                                                           \
    if (DO_STAGE) {                                                              \
      const int so = (((T) + 3) & 3) * SLOT_ELEMS;                               \
      gload_lds16(dA0 + so, pA0); gload_lds16(dA1 + so, pA1);                    \
      gload_lds16(dB0 + so, pB0); gload_lds16(dB1 + so, pB1);                    \
      pA0 += 32; pA1 += 32; pB0 += 32; pB1 += 32;                                \
    }                                                                            \
    const u16* sl = &lds[((T) & 3) * SLOT_ELEMS];                                \
    bf16x8 af[8], bfr[4];                                                        \
    _Pragma("unroll")                                                            \
    for (int mi = 0; mi < 8; ++mi)                                               \
      af[mi] = *(const bf16x8*)&sl[(wm * 128 + mi * 16 + lr) * 32 + lk];         \
    _Pragma("unroll")                                                            \
    for (int ni = 0; ni < 4; ++ni)                                               \
      bfr[ni] = *(const bf16x8*)&sl[8192 + (wn * 64 + ni * 16 + lr) * 32 + lk];  \
    __builtin_amdgcn_s_setprio(1);                                               \
    _Pragma("unroll")                                                            \
    for (int mi = 0; mi < 8; ++mi)                                               \
      _Pragma("unroll")                                                          \
      for (int ni = 0; ni < 4; ++ni)                                             \
        acc[mi][ni] = __builtin_amdgcn_mfma_f32_16x16x32_bf16(af[mi], bfr[ni],   \
                                                              acc[mi][ni], 0, 0, 0); \
    __builtin_amdgcn_s_setprio(0);                                               \
    if (DO_WAIT) asm volatile("s_waitcnt vmcnt(%0)" :: "n"(VM) : "memory");      \
    if (DO_BAR) { __builtin_amdgcn_s_barrier(); __builtin_amdgcn_sched_barrier(0); } \
  } while (0)

template <typename OutT>
__global__ __launch_bounds__(512, 2) void gemm256(const u16* __restrict__ A,
                                                  const u16* __restrict__ Bt,
                                                  OutT* __restrict__ C,
                                                  int M, int N, int K) {
    __shared__ u16 lds[4 * SLOT_ELEMS];   // 128 KiB
    const int tid  = threadIdx.x;
    const int lane = tid & 63;
    const int wid  = tid >> 6;
    const int wm = wid >> 2;           // 0..1 -> 128 rows each
    const int wn = wid & 3;            // 0..3 -> 64 cols each
    const int lr = lane & 15;
    const int lk = (lane >> 4) << 3;   // k elem offset 0,8,16,24

    // XCD-bijective block swizzle (gridDim.x % 8 == 0)
    const int nwg = gridDim.x;
    const int cpx = nwg >> 3;
    const int bid = blockIdx.x;
    const int swz = (bid & 7) * cpx + (bid >> 3);
    const int numM = M >> 8;
    const size_t rowBase = (size_t)(swz % numM) << 8;
    const size_t colBase = (size_t)(swz / numM) << 8;

    // staging: per K-tile, A = 256x32 bf16 = 16 KB = 1024 chunks of 16 B;
    // 512 threads x 2 chunks; same for B. 4 load-instrs per thread per K-tile.
    const int c0 = tid, c1 = tid + 512;
    const u16* pA0 = A  + (rowBase + (c0 >> 2)) * (size_t)K + ((c0 & 3) << 3);
    const u16* pA1 = A  + (rowBase + (c1 >> 2)) * (size_t)K + ((c1 & 3) << 3);
    const u16* pB0 = Bt + (colBase + (c0 >> 2)) * (size_t)K + ((c0 & 3) << 3);
    const u16* pB1 = Bt + (colBase + (c1 >> 2)) * (size_t)K + ((c1 & 3) << 3);
    u16* dA0 = &lds[0] + c0 * 8;
    u16* dA1 = &lds[0] + c1 * 8;
    u16* dB0 = &lds[0] + 8192 + c0 * 8;
    u16* dB1 = &lds[0] + 8192 + c1 * 8;

    f32x4 acc[8][4];
#pragma unroll
    for (int i = 0; i < 8; ++i)
#pragma unroll
        for (int j = 0; j < 4; ++j)
            acc[i][j] = (f32x4){0.f, 0.f, 0.f, 0.f};

    const int nsteps = K >> 5;

    // prologue: stage slots 0..2 (12 loads/thread), wait slot 0 only
    for (int s = 0; s < 3; ++s) {
        const int so = s * SLOT_ELEMS;
        gload_lds16(dA0 + so, pA0); gload_lds16(dA1 + so, pA1);
        gload_lds16(dB0 + so, pB0); gload_lds16(dB1 + so, pB1);
        pA0 += 32; pA1 += 32; pB0 += 32; pB1 += 32;
    }
    asm volatile("s_waitcnt vmcnt(8)" ::: "memory");
    __builtin_amdgcn_s_barrier();
    __builtin_amdgcn_sched_barrier(0);

    int t = 0;
    for (; t < nsteps - 3; ++t)
        KSTEP(t, true,  true, 8, true);
    KSTEP(t, false, true, 4, true);  ++t;   // last stage (nsteps-1) still in flight
    KSTEP(t, false, true, 0, true);  ++t;   // drain
    KSTEP(t, false, false, 0, false);       // final compute, no barrier needed

    // epilogue: C/D layout col = lane&15, row = 4*(lane>>4) + r
#pragma unroll
    for (int mi = 0; mi < 8; ++mi)
#pragma unroll
        for (int ni = 0; ni < 4; ++ni)
#pragma unroll
            for (int r = 0; r < 4; ++r) {
                size_t row = rowBase + wm * 128 + mi * 16 + ((lane >> 4) << 2) + r;
                size_t col = colBase + wn * 64 + ni * 16 + lr;
                store_out(&C[row * (size_t)N + col], acc[mi][ni][r]);
            }
}

extern "C" void kernel_launch(void* const* d_in, const int* in_sizes, int n_in,
                              void* d_out, int out_size, void* d_ws, size_t ws_size,
                              hipStream_t stream) {
    const float* hidden    = (const float*)d_in[0];   // [T][E] fp32
    const int*   positions = (const int*)d_in[1];     // [T] int32
    const float* w_qkv     = (const float*)d_in[2];   // [E][6144] fp32
    const float* w_o       = (const float*)d_in[3];   // [QSZ][E] fp32
    float* out = (float*)d_out;                       // [T][E] fp32

    // workspace layout (bf16): H 64MB | WqT 32MB | WoT 32MB | Q 64MB = 192MB
    u16* Hb  = (u16*)d_ws;
    u16* WqT = Hb  + (size_t)T_DIM * E_DIM;
    u16* WoT = WqT + (size_t)QSZ * E_DIM;
    u16* Qb  = WoT + (size_t)E_DIM * QSZ;

    // 1) hidden fp32 -> bf16
    convert_f32_bf16<<<2048, 256, 0, stream>>>(hidden, Hb, (size_t)T_DIM * E_DIM / 4);

    // 2) weight transposes+converts
    dim3 tb(32, 8);
    transpose_conv<<<dim3(QSZ / 32, E_DIM / 32), tb, 0, stream>>>(w_qkv, WqT, E_DIM, QSZ, QKV_COLS, 0);
    transpose_conv<<<dim3(E_DIM / 32, QSZ / 32), tb, 0, stream>>>(w_o,   WoT, QSZ,   E_DIM, E_DIM,  0);

    // 3) Q = H @ Wq  (bf16 out): grid 32x16 = 512 tiles
    gemm256<u16><<<dim3((T_DIM / 256) * (QSZ / 256)), 512, 0, stream>>>(Hb, WqT, Qb, T_DIM, QSZ, E_DIM);

    // 4) NeoX RoPE in place on Q
    rope_kernel<<<4096, 256, 0, stream>>>(Qb, positions);

    // 5) out = Q @ Wo  (fp32 out)
    gemm256<float><<<dim3((T_DIM / 256) * (E_DIM / 256)), 512, 0, stream>>>(Qb, WoT, out, T_DIM, E_DIM, QSZ);
}

// Round 3
// 672.906 us; speedup vs baseline: 1.3191x; 1.0298x over previous
//
#include <hip/hip_runtime.h>
#include <hip/hip_bf16.h>
#include <stdint.h>

// Problem constants (CausalSelfAttention_22703197127379)
#define T_DIM 8192
#define E_DIM 4096
#define NQH   32
#define HD    128
#define QSZ   (NQH * HD)          // 4096
#define QKV_COLS 6144             // Q_SIZE + 2*KV_SIZE (w_qkv leading dim)

typedef unsigned short u16;
typedef __attribute__((ext_vector_type(8))) short   bf16x8;
typedef __attribute__((ext_vector_type(4))) float   f32x4;
typedef __attribute__((ext_vector_type(4))) unsigned short u16x4;

__device__ __forceinline__ u16 f2bf(float f) {
    uint32_t u = __float_as_uint(f);
    u += 0x7fffu + ((u >> 16) & 1u);   // round-to-nearest-even
    return (u16)(u >> 16);
}
__device__ __forceinline__ float bf2f(u16 u) {
    return __uint_as_float(((uint32_t)u) << 16);
}

// async global->LDS, 16 bytes per lane (dest = wave-uniform base + lane*16)
__device__ __forceinline__ void gload_lds16(u16* lds, const u16* g) {
    __builtin_amdgcn_global_load_lds(
        (const __attribute__((address_space(1))) uint32_t*)g,
        (__attribute__((address_space(3))) uint32_t*)lds,
        16, 0, 0);
}

// ---------------- fp32 -> bf16 elementwise convert (vectorized) ----------------
__global__ void convert_f32_bf16(const float* __restrict__ in, u16* __restrict__ out, size_t n4) {
    size_t i = (size_t)blockIdx.x * blockDim.x + threadIdx.x;
    size_t stride = (size_t)gridDim.x * blockDim.x;
    for (; i < n4; i += stride) {
        float4 v = ((const float4*)in)[i];
        u16x4 o;
        o.x = f2bf(v.x); o.y = f2bf(v.y); o.z = f2bf(v.z); o.w = f2bf(v.w);
        ((u16x4*)out)[i] = o;
    }
}

// ---------------- fp32 [K][ldW] (col slice) -> bf16 transposed [N][K] ----------------
__global__ void transpose_conv(const float* __restrict__ W, u16* __restrict__ Wt,
                               int K, int N, int ldW, int colOff) {
    __shared__ float tile[32][33];
    const int tx = threadIdx.x, ty = threadIdx.y;
    const int n0 = blockIdx.x * 32, k0 = blockIdx.y * 32;
#pragma unroll
    for (int j = 0; j < 4; ++j) {
        int k = k0 + ty + j * 8;
        tile[ty + j * 8][tx] = W[(size_t)k * ldW + colOff + n0 + tx];
    }
    __syncthreads();
#pragma unroll
    for (int j = 0; j < 4; ++j) {
        int n = n0 + ty + j * 8;
        Wt[(size_t)n * K + k0 + tx] = f2bf(tile[tx][ty + j * 8]);
    }
}

// ---------------- NeoX RoPE, in-place on bf16 Q [T][QSZ] ----------------
__global__ void rope_kernel(u16* __restrict__ Q, const int* __restrict__ pos) {
    const size_t total = (size_t)T_DIM * (QSZ / 2);   // one thread per (d, d+64) pair
    size_t stride = (size_t)gridDim.x * blockDim.x;
    for (size_t idx = (size_t)blockIdx.x * blockDim.x + threadIdx.x; idx < total; idx += stride) {
        int t = (int)(idx >> 11);          // / 2048
        int r = (int)(idx & 2047);
        int h = r >> 6;
        int d = r & 63;
        size_t base = (size_t)t * QSZ + h * HD;
        float x1 = bf2f(Q[base + d]);
        float x2 = bf2f(Q[base + d + 64]);
        float inv = powf(10000.0f, -(float)d * (1.0f / 64.0f));
        float fr  = (float)pos[t] * inv;
        float s, c;
        sincosf(fr, &s, &c);
        Q[base + d]      = f2bf(x1 * c - x2 * s);
        Q[base + d + 64] = f2bf(x2 * c + x1 * s);
    }
}

// ---------------- pipelined bf16 GEMM: C[M][N] = A[M][K] * Bt[N][K]^T ----------------
// 256x256 tile, BK=32, 4-stage LDS ring (128 KiB), 8 waves (2M x 4N),
// counted vmcnt(8), one barrier per K-step, setprio around the MFMA cluster.
// T2 swizzle: LDS rows are 64 B = 4 chunks of 16 B; chunk (r,c) stored at
// position c ^ ((r>>1)&3) (involution). global_load_lds dest stays LINEAR;
// the permutation is applied to the per-lane GLOBAL source address (rule 21)
// and to the ds_read chunk index. Turns the 8-way read conflict
// (banks (16r+4c)%32, 16 rows x fixed chunk) into a free 2-way.
__device__ __forceinline__ void store_out(u16* p, float v)  { *p = f2bf(v); }
__device__ __forceinline__ void store_out(float* p, float v){ *p = v; }

#define SLOT_ELEMS 16384   // A 8192 + B 8192 u16 per stage (32 KB)

#define KSTEP(T, DO_STAGE, DO_WAIT, VM, DO_BAR)                                  \
  do {                                                                           \
    if (DO_STAGE) {                                                              \
      const int so = (((T) + 3) & 3) * SLOT_ELEMS;                               \
      gload_lds16(dA0 + so, pA0); gload_lds16(dA1 + so, pA1);                    \
      gload_lds16(dB0 + so, pB0); gload_lds16(dB1 + so, pB1);                    \
      pA0 += 32; pA1 += 32; pB0 += 32; pB1 += 32;                                \
    }                                                                            \
    const u16* sl = &lds[((T) & 3) * SLOT_ELEMS];                                \
    bf16x8 af[8], bfr[4];                                                        \
    _Pragma("unroll")                                                            \
    for (int mi = 0; mi < 8; ++mi)                                               \
      af[mi] = *(const bf16x8*)&sl[(wm * 128 + mi * 16 + lr) * 32 + lsw];        \
    _Pragma("unroll")                                                            \
    for (int ni = 0; ni < 4; ++ni)                                               \
      bfr[ni] = *(const bf16x8*)&sl[8192 + (wn * 64 + ni * 16 + lr) * 32 + lsw]; \
    __builtin_amdgcn_s_setprio(1);                                               \
    _Pragma("unroll")                                                            \
    for (int mi = 0; mi < 8; ++mi)                                               \
      _Pragma("unroll")                                                          \
      for (int ni = 0; ni < 4; ++ni)                                             \
        acc[mi][ni] = __builtin_amdgcn_mfma_f32_16x16x32_bf16(af[mi], bfr[ni],   \
                                                              acc[mi][ni], 0, 0, 0); \
    __builtin_amdgcn_s_setprio(0);                                               \
    if (DO_WAIT) asm volatile("s_waitcnt vmcnt(%0)" :: "n"(VM) : "memory");      \
    if (DO_BAR) { __builtin_amdgcn_s_barrier(); __builtin_amdgcn_sched_barrier(0); } \
  } while (0)

template <typename OutT>
__global__ __launch_bounds__(512, 2) void gemm256(const u16* __restrict__ A,
                                                  const u16* __restrict__ Bt,
                                                  OutT* __restrict__ C,
                                                  int M, int N, int K) {
    __shared__ u16 lds[4 * SLOT_ELEMS];   // 128 KiB
    const int tid  = threadIdx.x;
    const int lane = tid & 63;
    const int wid  = tid >> 6;
    const int wm = wid >> 2;           // 0..1 -> 128 rows each
    const int wn = wid & 3;            // 0..3 -> 64 cols each
    const int lr = lane & 15;
    // swizzled read chunk: ((lane>>4) ^ ((lr>>1)&3)) * 8 elems.
    // (row base is a multiple of 16, so (row>>1)&3 == (lr>>1)&3 for all mi.)
    const int lsw = (((lane >> 4) ^ ((lr >> 1) & 3)) << 3);

    // XCD-bijective block swizzle (gridDim.x % 8 == 0)
    const int nwg = gridDim.x;
    const int cpx = nwg >> 3;
    const int bid = blockIdx.x;
    const int swz = (bid & 7) * cpx + (bid >> 3);
    const int numM = M >> 8;
    const size_t rowBase = (size_t)(swz % numM) << 8;
    const size_t colBase = (size_t)(swz / numM) << 8;

    // staging: per K-tile, A = 256x32 bf16 = 16 KB = 1024 chunks of 16 B;
    // 512 threads x 2 chunks; same for B. LDS dest linear at chunk index c;
    // global source fetches chunk c ^ ((row>>1)&3)  (row = chunk>>2).
    const int c0 = tid, c1 = tid + 512;
    const int k0 = ((c0 & 3) ^ ((c0 >> 3) & 3)) << 3;
    const int k1 = ((c1 & 3) ^ ((c1 >> 3) & 3)) << 3;
    const u16* pA0 = A  + (rowBase + (c0 >> 2)) * (size_t)K + k0;
    const u16* pA1 = A  + (rowBase + (c1 >> 2)) * (size_t)K + k1;
    const u16* pB0 = Bt + (colBase + (c0 >> 2)) * (size_t)K + k0;
    const u16* pB1 = Bt + (colBase + (c1 >> 2)) * (size_t)K + k1;
    u16* dA0 = &lds[0] + c0 * 8;
    u16* dA1 = &lds[0] + c1 * 8;
    u16* dB0 = &lds[0] + 8192 + c0 * 8;
    u16* dB1 = &lds[0] + 8192 + c1 * 8;

    f32x4 acc[8][4];
#pragma unroll
    for (int i = 0; i < 8; ++i)
#pragma unroll
        for (int j = 0; j < 4; ++j)
            acc[i][j] = (f32x4){0.f, 0.f, 0.f, 0.f};

    const int nsteps = K >> 5;

    // prologue: stage slots 0..2 (12 loads/thread), wait slot 0 only
    for (int s = 0; s < 3; ++s) {
        const int so = s * SLOT_ELEMS;
        gload_lds16(dA0 + so, pA0); gload_lds16(dA1 + so, pA1);
        gload_lds16(dB0 + so, pB0); gload_lds16(dB1 + so, pB1);
        pA0 += 32; pA1 += 32; pB0 += 32; pB1 += 32;
    }
    asm volatile("s_waitcnt vmcnt(8)" ::: "memory");
    __builtin_amdgcn_s_barrier();
    __builtin_amdgcn_sched_barrier(0);

    int t = 0;
    for (; t < nsteps - 3; ++t)
        KSTEP(t, true,  true, 8, true);
    KSTEP(t, false, true, 4, true);  ++t;   // last stage (nsteps-1) still in flight
    KSTEP(t, false, true, 0, true);  ++t;   // drain
    KSTEP(t, false, false, 0, false);       // final compute, no barrier needed

    // epilogue: C/D layout col = lane&15, row = 4*(lane>>4) + r
#pragma unroll
    for (int mi = 0; mi < 8; ++mi)
#pragma unroll
        for (int ni = 0; ni < 4; ++ni)
#pragma unroll
            for (int r = 0; r < 4; ++r) {
                size_t row = rowBase + wm * 128 + mi * 16 + ((lane >> 4) << 2) + r;
                size_t col = colBase + wn * 64 + ni * 16 + lr;
                store_out(&C[row * (size_t)N + col], acc[mi][ni][r]);
            }
}

extern "C" void kernel_launch(void* const* d_in, const int* in_sizes, int n_in,
                              void* d_out, int out_size, void* d_ws, size_t ws_size,
                              hipStream_t stream) {
    const float* hidden    = (const float*)d_in[0];   // [T][E] fp32
    const int*   positions = (const int*)d_in[1];     // [T] int32
    const float* w_qkv     = (const float*)d_in[2];   // [E][6144] fp32
    const float* w_o       = (const float*)d_in[3];   // [QSZ][E] fp32
    float* out = (float*)d_out;                       // [T][E] fp32

    // workspace layout (bf16): H 64MB | WqT 32MB | WoT 32MB | Q 64MB = 192MB
    u16* Hb  = (u16*)d_ws;
    u16* WqT = Hb  + (size_t)T_DIM * E_DIM;
    u16* WoT = WqT + (size_t)QSZ * E_DIM;
    u16* Qb  = WoT + (size_t)E_DIM * QSZ;

    // 1) hidden fp32 -> bf16
    convert_f32_bf16<<<2048, 256, 0, stream>>>(hidden, Hb, (size_t)T_DIM * E_DIM / 4);

    // 2) weight transposes+converts
    dim3 tb(32, 8);
    transpose_conv<<<dim3(QSZ / 32, E_DIM / 32), tb, 0, stream>>>(w_qkv, WqT, E_DIM, QSZ, QKV_COLS, 0);
    transpose_conv<<<dim3(E_DIM / 32, QSZ / 32), tb, 0, stream>>>(w_o,   WoT, QSZ,   E_DIM, E_DIM,  0);

    // 3) Q = H @ Wq  (bf16 out): grid 32x16 = 512 tiles
    gemm256<u16><<<dim3((T_DIM / 256) * (QSZ / 256)), 512, 0, stream>>>(Hb, WqT, Qb, T_DIM, QSZ, E_DIM);

    // 4) NeoX RoPE in place on Q
    rope_kernel<<<4096, 256, 0, stream>>>(Qb, positions);

    // 5) out = Q @ Wo  (fp32 out)
    gemm256<float><<<dim3((T_DIM / 256) * (E_DIM / 256)), 512, 0, stream>>>(Qb, WoT, out, T_DIM, E_DIM, QSZ);
}

// Round 4
// 615.873 us; speedup vs baseline: 1.4412x; 1.0926x over previous
//
#include <hip/hip_runtime.h>
#include <hip/hip_bf16.h>
#include <stdint.h>

// Problem constants (CausalSelfAttention_22703197127379)
#define T_DIM 8192
#define E_DIM 4096
#define NQH   32
#define HD    128
#define QSZ   (NQH * HD)          // 4096
#define QKV_COLS 6144             // Q_SIZE + 2*KV_SIZE (w_qkv leading dim)

typedef unsigned short u16;
typedef __attribute__((ext_vector_type(8))) short   bf16x8;
typedef __attribute__((ext_vector_type(4))) float   f32x4;
typedef __attribute__((ext_vector_type(4))) unsigned short u16x4;

__device__ __forceinline__ u16 f2bf(float f) {
    uint32_t u = __float_as_uint(f);
    u += 0x7fffu + ((u >> 16) & 1u);   // round-to-nearest-even
    return (u16)(u >> 16);
}
__device__ __forceinline__ float bf2f(u16 u) {
    return __uint_as_float(((uint32_t)u) << 16);
}

// async global->LDS, 16 bytes per lane (dest = wave-uniform base + lane*16)
__device__ __forceinline__ void gload_lds16(u16* lds, const u16* g) {
    __builtin_amdgcn_global_load_lds(
        (const __attribute__((address_space(1))) uint32_t*)g,
        (__attribute__((address_space(3))) uint32_t*)lds,
        16, 0, 0);
}

// ---------------- fp32 -> bf16 elementwise convert (vectorized) ----------------
__global__ void convert_f32_bf16(const float* __restrict__ in, u16* __restrict__ out, size_t n4) {
    size_t i = (size_t)blockIdx.x * blockDim.x + threadIdx.x;
    size_t stride = (size_t)gridDim.x * blockDim.x;
    for (; i < n4; i += stride) {
        float4 v = ((const float4*)in)[i];
        u16x4 o;
        o.x = f2bf(v.x); o.y = f2bf(v.y); o.z = f2bf(v.z); o.w = f2bf(v.w);
        ((u16x4*)out)[i] = o;
    }
}

// ---------------- fp32 [K][ldW] (col slice) -> bf16 transposed [N][K] ----------------
__global__ void transpose_conv(const float* __restrict__ W, u16* __restrict__ Wt,
                               int K, int N, int ldW, int colOff) {
    __shared__ float tile[32][33];
    const int tx = threadIdx.x, ty = threadIdx.y;
    const int n0 = blockIdx.x * 32, k0 = blockIdx.y * 32;
#pragma unroll
    for (int j = 0; j < 4; ++j) {
        int k = k0 + ty + j * 8;
        tile[ty + j * 8][tx] = W[(size_t)k * ldW + colOff + n0 + tx];
    }
    __syncthreads();
#pragma unroll
    for (int j = 0; j < 4; ++j) {
        int n = n0 + ty + j * 8;
        Wt[(size_t)n * K + k0 + tx] = f2bf(tile[tx][ty + j * 8]);
    }
}

// ---------------- NeoX RoPE, in-place on bf16 Q [T][QSZ] ----------------
__global__ void rope_kernel(u16* __restrict__ Q, const int* __restrict__ pos) {
    const size_t total = (size_t)T_DIM * (QSZ / 2);   // one thread per (d, d+64) pair
    size_t stride = (size_t)gridDim.x * blockDim.x;
    for (size_t idx = (size_t)blockIdx.x * blockDim.x + threadIdx.x; idx < total; idx += stride) {
        int t = (int)(idx >> 11);          // / 2048
        int r = (int)(idx & 2047);
        int h = r >> 6;
        int d = r & 63;
        size_t base = (size_t)t * QSZ + h * HD;
        float x1 = bf2f(Q[base + d]);
        float x2 = bf2f(Q[base + d + 64]);
        float inv = powf(10000.0f, -(float)d * (1.0f / 64.0f));
        float fr  = (float)pos[t] * inv;
        float s, c;
        sincosf(fr, &s, &c);
        Q[base + d]      = f2bf(x1 * c - x2 * s);
        Q[base + d + 64] = f2bf(x2 * c + x1 * s);
    }
}

// ======================= 8-phase pipelined bf16 GEMM =======================
// C[M][N] = A[M][K] * Bt[N][K]^T. 256x256 tile, BK=64, 8 waves (2M x 4N),
// 2 K-tile LDS buffers (128 KiB), 8 phases/iter covering 2 K-tiles.
// Per phase: {ds_read subtile || issue 1 half-tile stage} -> barrier ->
// 16-MFMA cluster (setprio) -> barrier. vmcnt(4) only at P3/P7.
// Stage map (iter i): P0,P1 -> buf1.A0,A1 (tile 2i+1); P2..P5 -> buf0 (tile
// 2i+2, order B0,B1,A0,A1); P6,P7 -> buf1.B0,B1 (tile 2i+3).
// vmcnt(4)@P3 drains all of buf1(tile 2i+1) before P4 reads; vmcnt(4)@P7
// drains all of buf0(tile 2i+2) before next-iter P0. Every LDS overwrite is
// >=2 barriers after the last read of that half-tile.
// Swizzle: row of 64 K-elems = 8 chunks of 16B; chunk (r,c) stored at c^(r&7);
// global source pre-swizzled, ds_read XORs the same pattern (rule 21).
__device__ __forceinline__ void store_out(u16* p, float v)  { *p = f2bf(v); }
__device__ __forceinline__ void store_out(float* p, float v){ *p = v; }

#define BAR() do { __builtin_amdgcn_sched_barrier(0); __builtin_amdgcn_s_barrier(); \
                   __builtin_amdgcn_sched_barrier(0); } while (0)
#define VMC(N) asm volatile("s_waitcnt vmcnt(%0)" :: "n"(N) : "memory")

// stage one half-tile (128 rows x 64 K, one operand): 2 gloads/thread
#define STG_A(buf, h, kOff) do { \
    const u16* s_ = sA + (size_t)(h) * 128 * K + (kOff); \
    u16* d_ = dL + (buf) * 32768 + (h) * 8192; \
    gload_lds16(d_, s_); gload_lds16(d_ + 4096, s_ + (size_t)64 * K); } while (0)
#define STG_B(buf, h, kOff) do { \
    const u16* s_ = sB + (size_t)(h) * 128 * K + (kOff); \
    u16* d_ = dL + 16384 + (buf) * 32768 + (h) * 8192; \
    gload_lds16(d_, s_); gload_lds16(d_ + 4096, s_ + (size_t)64 * K); } while (0)

// read A frags mi in [miBase, miBase+4), both K-slices, from buf's wm-half
#define RD_A(buf, miBase) do { _Pragma("unroll") \
    for (int m = 0; m < 4; ++m) { \
        const u16* p_ = lds + (buf) * 32768 + wm * 8192 + ((miBase) + m) * 1024 + aRow; \
        aK0[m] = *(const bf16x8*)(p_ + cOf0); \
        aK1[m] = *(const bf16x8*)(p_ + cOf1); } } while (0)
// read B frags ni in [niBase, niBase+2), both K-slices
#define RD_B(buf, niBase, d0, d1) do { _Pragma("unroll") \
    for (int n = 0; n < 2; ++n) { \
        const u16* p_ = lds + (buf) * 32768 + 16384 + (wn >> 1) * 8192 + \
                        ((wn & 1) * 64 + ((niBase) + n) * 16) * 64 + aRow; \
        d0[n] = *(const bf16x8*)(p_ + cOf0); \
        d1[n] = *(const bf16x8*)(p_ + cOf1); } } while (0)

#define MM(miBase, niBase, bq0, bq1) do { \
    __builtin_amdgcn_s_setprio(1); \
    _Pragma("unroll") for (int m = 0; m < 4; ++m) \
    _Pragma("unroll") for (int n = 0; n < 2; ++n) { \
        acc[(miBase) + m][(niBase) + n] = __builtin_amdgcn_mfma_f32_16x16x32_bf16( \
            aK0[m], bq0[n], acc[(miBase) + m][(niBase) + n], 0, 0, 0); \
        acc[(miBase) + m][(niBase) + n] = __builtin_amdgcn_mfma_f32_16x16x32_bf16( \
            aK1[m], bq1[n], acc[(miBase) + m][(niBase) + n], 0, 0, 0); } \
    __builtin_amdgcn_s_setprio(0); } while (0)

template <typename OutT>
__global__ __launch_bounds__(512, 2) void gemm256(const u16* __restrict__ A,
                                                  const u16* __restrict__ Bt,
                                                  OutT* __restrict__ C,
                                                  int M, int N, int K) {
    __shared__ u16 lds[65536];   // 2 bufs x (A 256x64 + B 256x64) bf16 = 128 KiB
    const int tid  = threadIdx.x;
    const int lane = tid & 63;
    const int wid  = tid >> 6;
    const int wm = wid >> 2;           // 0..1 -> 128 rows each
    const int wn = wid & 3;            // 0..3 -> 64 cols each
    const int lr  = lane & 15;
    const int kq  = lane >> 4;         // 0..3
    const int lr7 = lr & 7;
    const int aRow = lr * 64;                       // row offset within half (elems)
    const int cOf0 = ((kq) ^ lr7) << 3;             // K-slice 0 chunk (swizzled)
    const int cOf1 = ((4 + kq) ^ lr7) << 3;         // K-slice 1 chunk

    // XCD-bijective block swizzle (gridDim.x % 8 == 0)
    const int nwg = gridDim.x;
    const int cpx = nwg >> 3;
    const int bid = blockIdx.x;
    const int swz = (bid & 7) * cpx + (bid >> 3);
    const int numM = M >> 8;
    const size_t rowBase = (size_t)(swz % numM) << 8;
    const size_t colBase = (size_t)(swz / numM) << 8;

    // staging addresses: half-tile = 1024 chunks of 16B; thread owns chunks
    // tid (row r0=tid>>3) and tid+512 (row r0+64); src col pre-swizzled.
    const int r0 = tid >> 3;
    const int cS = (((tid & 7) ^ (r0 & 7)) << 3);
    const u16* sA = A  + (rowBase + r0) * (size_t)K + cS;
    const u16* sB = Bt + (colBase + r0) * (size_t)K + cS;
    u16* dL = &lds[0] + tid * 8;       // linear chunk dest (+4096 elems for chunk tid+512)

    f32x4 acc[8][4];
#pragma unroll
    for (int i = 0; i < 8; ++i)
#pragma unroll
        for (int j = 0; j < 4; ++j)
            acc[i][j] = (f32x4){0.f, 0.f, 0.f, 0.f};

    bf16x8 aK0[4], aK1[4], b01K0[2], b01K1[2], b23K0[2], b23K1[2];

    // prologue: buf0 <- tile0 (4 half-tiles), buf1.B0,B1 <- tile1. 12 loads;
    // vmcnt(4) drains buf0, leaves buf1.B in flight (steady-state entry).
    STG_A(0, 0, 0); STG_A(0, 1, 0); STG_B(0, 0, 0); STG_B(0, 1, 0);
    STG_B(1, 0, 64); STG_B(1, 1, 64);
    VMC(4);
    BAR();

    const int nIter = K >> 7;          // K/128, K % 128 == 0
    for (int it = 0; it < nIter; ++it) {
        const int k1  = ((it << 1) + 1) << 6;                    // tile 2i+1 (always valid)
        const int kt2 = ((it << 1) + 2) << 6;
        const int kt3 = ((it << 1) + 3) << 6;
        const int k2c = (kt2 <= K - 64) ? kt2 : 0;               // clamp OOB tail stages
        const int k3c = (kt3 <= K - 64) ? kt3 : 0;               // (data never consumed)

        // P0
        RD_A(0, 0); RD_B(0, 0, b01K0, b01K1);
        STG_A(1, 0, k1);
        BAR();
        MM(0, 0, b01K0, b01K1);
        BAR();
        // P1
        RD_B(0, 2, b23K0, b23K1);
        STG_A(1, 1, k1);
        BAR();
        MM(0, 2, b23K0, b23K1);
        BAR();
        // P2
        RD_A(0, 4);
        STG_B(0, 0, k2c);
        BAR();
        MM(4, 2, b23K0, b23K1);
        BAR();
        // P3
        STG_B(0, 1, k2c);
        VMC(4);
        BAR();
        MM(4, 0, b01K0, b01K1);
        BAR();
        // P4
        RD_A(1, 0); RD_B(1, 0, b01K0, b01K1);
        STG_A(0, 0, k2c);
        BAR();
        MM(0, 0, b01K0, b01K1);
        BAR();
        // P5
        RD_B(1, 2, b23K0, b23K1);
        STG_A(0, 1, k2c);
        BAR();
        MM(0, 2, b23K0, b23K1);
        BAR();
        // P6
        RD_A(1, 4);
        STG_B(1, 0, k3c);
        BAR();
        MM(4, 2, b23K0, b23K1);
        BAR();
        // P7
        STG_B(1, 1, k3c);
        VMC(4);
        BAR();
        MM(4, 0, b01K0, b01K1);
        BAR();
    }

    asm volatile("s_waitcnt vmcnt(0)" ::: "memory");   // drain leftover stages

    // epilogue: C/D layout col = lane&15, row = 4*(lane>>4) + r
#pragma unroll
    for (int mi = 0; mi < 8; ++mi)
#pragma unroll
        for (int ni = 0; ni < 4; ++ni)
#pragma unroll
            for (int r = 0; r < 4; ++r) {
                size_t row = rowBase + wm * 128 + mi * 16 + (kq << 2) + r;
                size_t col = colBase + wn * 64 + ni * 16 + lr;
                store_out(&C[row * (size_t)N + col], acc[mi][ni][r]);
            }
}

extern "C" void kernel_launch(void* const* d_in, const int* in_sizes, int n_in,
                              void* d_out, int out_size, void* d_ws, size_t ws_size,
                              hipStream_t stream) {
    const float* hidden    = (const float*)d_in[0];   // [T][E] fp32
    const int*   positions = (const int*)d_in[1];     // [T] int32
    const float* w_qkv     = (const float*)d_in[2];   // [E][6144] fp32
    const float* w_o       = (const float*)d_in[3];   // [QSZ][E] fp32
    float* out = (float*)d_out;                       // [T][E] fp32

    // workspace layout (bf16): H 64MB | WqT 32MB | WoT 32MB | Q 64MB = 192MB
    u16* Hb  = (u16*)d_ws;
    u16* WqT = Hb  + (size_t)T_DIM * E_DIM;
    u16* WoT = WqT + (size_t)QSZ * E_DIM;
    u16* Qb  = WoT + (size_t)E_DIM * QSZ;

    // 1) hidden fp32 -> bf16
    convert_f32_bf16<<<2048, 256, 0, stream>>>(hidden, Hb, (size_t)T_DIM * E_DIM / 4);

    // 2) weight transposes+converts
    dim3 tb(32, 8);
    transpose_conv<<<dim3(QSZ / 32, E_DIM / 32), tb, 0, stream>>>(w_qkv, WqT, E_DIM, QSZ, QKV_COLS, 0);
    transpose_conv<<<dim3(E_DIM / 32, QSZ / 32), tb, 0, stream>>>(w_o,   WoT, QSZ,   E_DIM, E_DIM,  0);

    // 3) Q = H @ Wq  (bf16 out): grid 32x16 = 512 tiles
    gemm256<u16><<<dim3((T_DIM / 256) * (QSZ / 256)), 512, 0, stream>>>(Hb, WqT, Qb, T_DIM, QSZ, E_DIM);

    // 4) NeoX RoPE in place on Q
    rope_kernel<<<4096, 256, 0, stream>>>(Qb, positions);

    // 5) out = Q @ Wo  (fp32 out)
    gemm256<float><<<dim3((T_DIM / 256) * (E_DIM / 256)), 512, 0, stream>>>(Qb, WoT, out, T_DIM, E_DIM, QSZ);
}

// Round 5
// 605.723 us; speedup vs baseline: 1.4654x; 1.0168x over previous
//
#include <hip/hip_runtime.h>
#include <hip/hip_bf16.h>
#include <stdint.h>

// Problem constants (CausalSelfAttention_22703197127379)
#define T_DIM 8192
#define E_DIM 4096
#define NQH   32
#define HD    128
#define QSZ   (NQH * HD)          // 4096
#define QKV_COLS 6144             // Q_SIZE + 2*KV_SIZE (w_qkv leading dim)

typedef unsigned short u16;
typedef __attribute__((ext_vector_type(8))) short   bf16x8;
typedef __attribute__((ext_vector_type(4))) float   f32x4;
typedef __attribute__((ext_vector_type(4))) unsigned short u16x4;

__device__ __forceinline__ u16 f2bf(float f) {
    uint32_t u = __float_as_uint(f);
    u += 0x7fffu + ((u >> 16) & 1u);   // round-to-nearest-even
    return (u16)(u >> 16);
}
__device__ __forceinline__ float bf2f(u16 u) {
    return __uint_as_float(((uint32_t)u) << 16);
}

// async global->LDS, 16 bytes per lane (dest = wave-uniform base + lane*16)
__device__ __forceinline__ void gload_lds16(u16* lds, const u16* g) {
    __builtin_amdgcn_global_load_lds(
        (const __attribute__((address_space(1))) uint32_t*)g,
        (__attribute__((address_space(3))) uint32_t*)lds,
        16, 0, 0);
}

// ---------------- fp32 -> bf16 elementwise convert (vectorized) ----------------
__global__ void convert_f32_bf16(const float* __restrict__ in, u16* __restrict__ out, size_t n4) {
    size_t i = (size_t)blockIdx.x * blockDim.x + threadIdx.x;
    size_t stride = (size_t)gridDim.x * blockDim.x;
    for (; i < n4; i += stride) {
        float4 v = ((const float4*)in)[i];
        u16x4 o;
        o.x = f2bf(v.x); o.y = f2bf(v.y); o.z = f2bf(v.z); o.w = f2bf(v.w);
        ((u16x4*)out)[i] = o;
    }
}

// ---------------- fp32 [K][ldW] (col slice) -> bf16 transposed [N][K] ----------------
__global__ void transpose_conv(const float* __restrict__ W, u16* __restrict__ Wt,
                               int K, int N, int ldW, int colOff) {
    __shared__ float tile[32][33];
    const int tx = threadIdx.x, ty = threadIdx.y;
    const int n0 = blockIdx.x * 32, k0 = blockIdx.y * 32;
#pragma unroll
    for (int j = 0; j < 4; ++j) {
        int k = k0 + ty + j * 8;
        tile[ty + j * 8][tx] = W[(size_t)k * ldW + colOff + n0 + tx];
    }
    __syncthreads();
#pragma unroll
    for (int j = 0; j < 4; ++j) {
        int n = n0 + ty + j * 8;
        Wt[(size_t)n * K + k0 + tx] = f2bf(tile[tx][ty + j * 8]);
    }
}

// ---------------- NeoX RoPE, in-place on bf16 Q [T][QSZ] ----------------
__global__ void rope_kernel(u16* __restrict__ Q, const int* __restrict__ pos) {
    const size_t total = (size_t)T_DIM * (QSZ / 2);   // one thread per (d, d+64) pair
    size_t stride = (size_t)gridDim.x * blockDim.x;
    for (size_t idx = (size_t)blockIdx.x * blockDim.x + threadIdx.x; idx < total; idx += stride) {
        int t = (int)(idx >> 11);          // / 2048
        int r = (int)(idx & 2047);
        int h = r >> 6;
        int d = r & 63;
        size_t base = (size_t)t * QSZ + h * HD;
        float x1 = bf2f(Q[base + d]);
        float x2 = bf2f(Q[base + d + 64]);
        float inv = powf(10000.0f, -(float)d * (1.0f / 64.0f));
        float fr  = (float)pos[t] * inv;
        float s, c;
        sincosf(fr, &s, &c);
        Q[base + d]      = f2bf(x1 * c - x2 * s);
        Q[base + d + 64] = f2bf(x2 * c + x1 * s);
    }
}

// ======================= read-ahead 8-phase bf16 GEMM =======================
// C[M][N] = A[M][K] * Bt[N][K]^T. 256x256 tile, BK=64, 8 waves (2M x 4N),
// 2 K-tile LDS buffers (128 KiB). 1 block/CU (LDS-capped) -> all barriers are
// CU-wide, so reads must overlap MFMA WITHIN the phase: each phase's ds_reads
// fetch the NEXT phase's operands and sit AFTER the barrier next to the MFMA
// cluster -> LDS pipe drains under the MFMA shadow (max, not sum).
// Phase p: STG(p) -> [vmcnt(4) @P3/P7] -> sched_barrier+s_barrier ->
//          ds_reads(p+1 operands) -> MFMA(p operands, read at p-1).
// Safety ledger:
//  - stage@q vs outstanding reads@q-1 (max barrier skew = 1 phase): all 8
//    pairs target disjoint LDS regions (checked exhaustively).
//  - vmcnt(4)@P3 drains exactly buf1 (stages prevP6,prevP7,P0,P1), @P7
//    exactly buf0 (P2..P5); publishing barrier follows BEFORE dependent
//    reads; sched_barrier(0) after s_barrier at P3/P7 pins those reads.
//  - compiler emits exact lgkmcnt for ds_read->MFMA deps (cross-phase regs).
//  - b01 has even/odd register sets (overlapping live ranges); a03/a47/b23
//    reuse windows are disjoint.
//  - OOB tail stages clamp to k=0 (staged, drained, never consumed).
__device__ __forceinline__ void store_out(u16* p, float v)  { *p = f2bf(v); }
__device__ __forceinline__ void store_out(float* p, float v){ *p = v; }

#define BARS()    do { __builtin_amdgcn_sched_barrier(0); __builtin_amdgcn_s_barrier(); } while (0)
#define BARSPUB() do { __builtin_amdgcn_sched_barrier(0); __builtin_amdgcn_s_barrier(); \
                       __builtin_amdgcn_sched_barrier(0); } while (0)
#define VMC(N) asm volatile("s_waitcnt vmcnt(%0)" :: "n"(N) : "memory")

// stage one half-tile (128 rows x 64 K, one operand): 2 gloads/thread
#define STG_A(buf, h, kOff) do { \
    const u16* s_ = sA + (size_t)(h) * 128 * K + (kOff); \
    u16* d_ = dL + (buf) * 32768 + (h) * 8192; \
    gload_lds16(d_, s_); gload_lds16(d_ + 4096, s_ + (size_t)64 * K); } while (0)
#define STG_B(buf, h, kOff) do { \
    const u16* s_ = sB + (size_t)(h) * 128 * K + (kOff); \
    u16* d_ = dL + 16384 + (buf) * 32768 + (h) * 8192; \
    gload_lds16(d_, s_); gload_lds16(d_ + 4096, s_ + (size_t)64 * K); } while (0)

// read A frags mi in [miBase, miBase+4), both K-slices
#define RD_A(buf, miBase, d0, d1) do { _Pragma("unroll") \
    for (int m = 0; m < 4; ++m) { \
        const u16* p_ = lds + (buf) * 32768 + wm * 8192 + ((miBase) + m) * 1024 + aRow; \
        d0[m] = *(const bf16x8*)(p_ + cOf0); \
        d1[m] = *(const bf16x8*)(p_ + cOf1); } } while (0)
// read B frags ni in [niBase, niBase+2), both K-slices
#define RD_B(buf, niBase, d0, d1) do { _Pragma("unroll") \
    for (int n = 0; n < 2; ++n) { \
        const u16* p_ = lds + (buf) * 32768 + 16384 + (wn >> 1) * 8192 + \
                        ((wn & 1) * 64 + ((niBase) + n) * 16) * 64 + aRow; \
        d0[n] = *(const bf16x8*)(p_ + cOf0); \
        d1[n] = *(const bf16x8*)(p_ + cOf1); } } while (0)

#define MM(miBase, niBase, A0, A1, B0, B1) do { \
    __builtin_amdgcn_s_setprio(1); \
    _Pragma("unroll") for (int m = 0; m < 4; ++m) \
    _Pragma("unroll") for (int n = 0; n < 2; ++n) { \
        acc[(miBase) + m][(niBase) + n] = __builtin_amdgcn_mfma_f32_16x16x32_bf16( \
            A0[m], B0[n], acc[(miBase) + m][(niBase) + n], 0, 0, 0); \
        acc[(miBase) + m][(niBase) + n] = __builtin_amdgcn_mfma_f32_16x16x32_bf16( \
            A1[m], B1[n], acc[(miBase) + m][(niBase) + n], 0, 0, 0); } \
    __builtin_amdgcn_s_setprio(0); } while (0)

template <typename OutT>
__global__ __launch_bounds__(512, 2) void gemm256(const u16* __restrict__ A,
                                                  const u16* __restrict__ Bt,
                                                  OutT* __restrict__ C,
                                                  int M, int N, int K) {
    __shared__ u16 lds[65536];   // 2 bufs x (A 256x64 + B 256x64) bf16 = 128 KiB
    const int tid  = threadIdx.x;
    const int lane = tid & 63;
    const int wid  = tid >> 6;
    const int wm = wid >> 2;           // 0..1 -> 128 rows each
    const int wn = wid & 3;            // 0..3 -> 64 cols each
    const int lr  = lane & 15;
    const int kq  = lane >> 4;         // 0..3
    const int lr7 = lr & 7;
    const int aRow = lr * 64;                       // row offset within half (elems)
    const int cOf0 = ((kq) ^ lr7) << 3;             // K-slice 0 chunk (swizzled)
    const int cOf1 = ((4 + kq) ^ lr7) << 3;         // K-slice 1 chunk

    // XCD-bijective block swizzle (gridDim.x % 8 == 0)
    const int nwg = gridDim.x;
    const int cpx = nwg >> 3;
    const int bid = blockIdx.x;
    const int swz = (bid & 7) * cpx + (bid >> 3);
    const int numM = M >> 8;
    const size_t rowBase = (size_t)(swz % numM) << 8;
    const size_t colBase = (size_t)(swz / numM) << 8;

    // staging addresses: half-tile = 1024 chunks of 16B; thread owns chunks
    // tid (row r0=tid>>3) and tid+512 (row r0+64); src col pre-swizzled.
    const int r0 = tid >> 3;
    const int cS = (((tid & 7) ^ (r0 & 7)) << 3);
    const u16* sA = A  + (rowBase + r0) * (size_t)K + cS;
    const u16* sB = Bt + (colBase + r0) * (size_t)K + cS;
    u16* dL = &lds[0] + tid * 8;       // linear chunk dest (+4096 elems for chunk tid+512)

    f32x4 acc[8][4];
#pragma unroll
    for (int i = 0; i < 8; ++i)
#pragma unroll
        for (int j = 0; j < 4; ++j)
            acc[i][j] = (f32x4){0.f, 0.f, 0.f, 0.f};

    bf16x8 a0K0[4], a0K1[4], a4K0[4], a4K1[4];
    bf16x8 b01eK0[2], b01eK1[2], b01oK0[2], b01oK1[2], b23K0[2], b23K1[2];

    // prologue: buf0 <- tile0, buf1.B <- tile1; drain buf0 (leave buf1.B in
    // flight), publish, then pre-read P0's operands (a03+b01_e of tile0).
    STG_A(0, 0, 0); STG_A(0, 1, 0); STG_B(0, 0, 0); STG_B(0, 1, 0);
    STG_B(1, 0, 64); STG_B(1, 1, 64);
    VMC(4);
    BARSPUB();
    RD_A(0, 0, a0K0, a0K1);
    RD_B(0, 0, b01eK0, b01eK1);

    const int nIter = K >> 7;          // K/128, K % 128 == 0
    for (int it = 0; it < nIter; ++it) {
        const int k1  = ((it << 1) + 1) << 6;                    // tile 2i+1 (always valid)
        const int kt2 = ((it << 1) + 2) << 6;
        const int kt3 = ((it << 1) + 3) << 6;
        const int k2c = (kt2 <= K - 64) ? kt2 : 0;               // clamp OOB tail stages
        const int k3c = (kt3 <= K - 64) ? kt3 : 0;               // (data never consumed)

        // P0: MFMA Q00 (a03,b01_e buf0) ; read b23(buf0) for P1
        STG_A(1, 0, k1);
        BARS();
        RD_B(0, 2, b23K0, b23K1);
        MM(0, 0, a0K0, a0K1, b01eK0, b01eK1);
        // P1: MFMA Q02 (a03,b23) ; read a47(buf0) for P2
        STG_A(1, 1, k1);
        BARS();
        RD_A(0, 4, a4K0, a4K1);
        MM(0, 2, a0K0, a0K1, b23K0, b23K1);
        // P2: MFMA Q42 (a47,b23) ; no reads
        STG_B(0, 0, k2c);
        BARS();
        MM(4, 2, a4K0, a4K1, b23K0, b23K1);
        // P3: drain buf1, publish ; MFMA Q40 (a47,b01_e) ; read a03+b01_o (buf1) for P4
        STG_B(0, 1, k2c);
        VMC(4);
        BARSPUB();
        RD_A(1, 0, a0K0, a0K1);
        RD_B(1, 0, b01oK0, b01oK1);
        MM(4, 0, a4K0, a4K1, b01eK0, b01eK1);
        // P4: MFMA Q00' (a03,b01_o buf1) ; read b23(buf1) for P5
        STG_A(0, 0, k2c);
        BARS();
        RD_B(1, 2, b23K0, b23K1);
        MM(0, 0, a0K0, a0K1, b01oK0, b01oK1);
        // P5: MFMA Q02' ; read a47(buf1) for P6
        STG_A(0, 1, k2c);
        BARS();
        RD_A(1, 4, a4K0, a4K1);
        MM(0, 2, a0K0, a0K1, b23K0, b23K1);
        // P6: MFMA Q42' ; no reads
        STG_B(1, 0, k3c);
        BARS();
        MM(4, 2, a4K0, a4K1, b23K0, b23K1);
        // P7: drain buf0, publish ; MFMA Q40' ; read a03+b01_e (buf0, next tile) for next P0
        STG_B(1, 1, k3c);
        VMC(4);
        BARSPUB();
        RD_A(0, 0, a0K0, a0K1);
        RD_B(0, 0, b01eK0, b01eK1);
        MM(4, 0, a4K0, a4K1, b01oK0, b01oK1);
    }

    asm volatile("s_waitcnt vmcnt(0)" ::: "memory");   // drain leftover stages

    // epilogue: C/D layout col = lane&15, row = 4*(lane>>4) + r
#pragma unroll
    for (int mi = 0; mi < 8; ++mi)
#pragma unroll
        for (int ni = 0; ni < 4; ++ni)
#pragma unroll
            for (int r = 0; r < 4; ++r) {
                size_t row = rowBase + wm * 128 + mi * 16 + (kq << 2) + r;
                size_t col = colBase + wn * 64 + ni * 16 + lr;
                store_out(&C[row * (size_t)N + col], acc[mi][ni][r]);
            }
}

extern "C" void kernel_launch(void* const* d_in, const int* in_sizes, int n_in,
                              void* d_out, int out_size, void* d_ws, size_t ws_size,
                              hipStream_t stream) {
    const float* hidden    = (const float*)d_in[0];   // [T][E] fp32
    const int*   positions = (const int*)d_in[1];     // [T] int32
    const float* w_qkv     = (const float*)d_in[2];   // [E][6144] fp32
    const float* w_o       = (const float*)d_in[3];   // [QSZ][E] fp32
    float* out = (float*)d_out;                       // [T][E] fp32

    // workspace layout (bf16): H 64MB | WqT 32MB | WoT 32MB | Q 64MB = 192MB
    u16* Hb  = (u16*)d_ws;
    u16* WqT = Hb  + (size_t)T_DIM * E_DIM;
    u16* WoT = WqT + (size_t)QSZ * E_DIM;
    u16* Qb  = WoT + (size_t)E_DIM * QSZ;

    // 1) hidden fp32 -> bf16
    convert_f32_bf16<<<2048, 256, 0, stream>>>(hidden, Hb, (size_t)T_DIM * E_DIM / 4);

    // 2) weight transposes+converts
    dim3 tb(32, 8);
    transpose_conv<<<dim3(QSZ / 32, E_DIM / 32), tb, 0, stream>>>(w_qkv, WqT, E_DIM, QSZ, QKV_COLS, 0);
    transpose_conv<<<dim3(E_DIM / 32, QSZ / 32), tb, 0, stream>>>(w_o,   WoT, QSZ,   E_DIM, E_DIM,  0);

    // 3) Q = H @ Wq  (bf16 out): grid 32x16 = 512 tiles
    gemm256<u16><<<dim3((T_DIM / 256) * (QSZ / 256)), 512, 0, stream>>>(Hb, WqT, Qb, T_DIM, QSZ, E_DIM);

    // 4) NeoX RoPE in place on Q
    rope_kernel<<<4096, 256, 0, stream>>>(Qb, positions);

    // 5) out = Q @ Wo  (fp32 out)
    gemm256<float><<<dim3((T_DIM / 256) * (E_DIM / 256)), 512, 0, stream>>>(Qb, WoT, out, T_DIM, E_DIM, QSZ);
}